// Round 1
// baseline (1243.848 us; speedup 1.0000x reference)
//
#include <hip/hip_runtime.h>

// E3nnSimpleEdgeBlock: out0[e,w] = C0*( sum_uv W000[u,v,w] a0[e,u] b0[e,v]
//                                      + 1/sqrt3 * sum_uv W110[u,v,w] dot(a1[e,u,:], b1[e,v,:]) )
// out1[e,w,k] = C1*( 1/sqrt3*( sum W011 a0[e,u] b1[e,v,k] + sum W101 a1[e,u,k] b0[e,v] )
//                   + 1/sqrt6 * sum W111 cross(a1[e,u,:], b1[e,v,:])[k] )
// out = [out0 (32) | out1 flattened w-major,k-minor (96)] per edge row of 128.

static constexpr float C_OUT0    = 0.022097086912079608f; // 1/sqrt(2048)
static constexpr float C_OUT1    = 0.03125f;              // 1/sqrt(1024)
static constexpr float INV_SQRT3 = 0.57735026918962576f;
static constexpr float INV_SQRT6 = 0.40824829046386302f;

#define EPB 8  // edges per block

__global__ __launch_bounds__(256) void e3nn_edge_f32(
    const float* __restrict__ x1, const float* __restrict__ x2,
    const float* __restrict__ W000, const float* __restrict__ W110,
    const float* __restrict__ W011, const float* __restrict__ W101,
    const float* __restrict__ W111, float* __restrict__ out, int E)
{
    // staged inputs for this block's 8 edges
    __shared__ __align__(16) float xs1[EPB][128];
    __shared__ __align__(16) float xs2[EPB][128];
    // pair features for fixed v: feat[e][u][ch], ch 0..10 (padded to 12 for float4 reads)
    __shared__ __align__(16) float feat[EPB][32][12];

    const int tid   = threadIdx.x;
    const int eBase = blockIdx.x * EPB;

    for (int i = tid; i < EPB * 128; i += 256) {
        int e = i >> 7, r = i & 127;
        if (eBase + e < E) {
            xs1[e][r] = x1[(size_t)(eBase + e) * 128 + r];
            xs2[e][r] = x2[(size_t)(eBase + e) * 128 + r];
        }
    }
    __syncthreads();

    const int w  = tid & 31;   // output w index owned by this thread
    const int le = tid >> 5;   // local edge 0..7

    float acc0 = 0.f, acc1x = 0.f, acc1y = 0.f, acc1z = 0.f;

    for (int v = 0; v < 32; ++v) {
        if (v) __syncthreads();  // previous iteration's feat reads complete

        // ---- feature phase: thread (le, u=w) computes 11 channels at this v ----
        {
            const int u = w;
            const float b0  = xs2[le][v];
            const float b1x = xs2[le][32 + 3 * v + 0];
            const float b1y = xs2[le][32 + 3 * v + 1];
            const float b1z = xs2[le][32 + 3 * v + 2];
            const float a0  = xs1[le][u];
            const float a1x = xs1[le][32 + 3 * u + 0];
            const float a1y = xs1[le][32 + 3 * u + 1];
            const float a1z = xs1[le][32 + 3 * u + 2];
            float* f = feat[le][u];
            f[0]  = a0 * b0;                                              // -> W000
            f[1]  = INV_SQRT3 * (a1x * b1x + a1y * b1y + a1z * b1z);      // -> W110
            f[2]  = INV_SQRT3 * (a0 * b1x);                               // -> W011 k=0
            f[3]  = INV_SQRT3 * (a0 * b1y);                               // k=1
            f[4]  = INV_SQRT3 * (a0 * b1z);                               // k=2
            f[5]  = INV_SQRT3 * (a1x * b0);                               // -> W101 k=0
            f[6]  = INV_SQRT3 * (a1y * b0);                               // k=1
            f[7]  = INV_SQRT3 * (a1z * b0);                               // k=2
            f[8]  = INV_SQRT6 * (a1y * b1z - a1z * b1y);                  // -> W111 k=0
            f[9]  = INV_SQRT6 * (a1z * b1x - a1x * b1z);                  // k=1
            f[10] = INV_SQRT6 * (a1x * b1y - a1y * b1x);                  // k=2
        }
        __syncthreads();

        // ---- accumulate phase: contract over u for this v ----
        const int wbase = v * 32 + w;  // W flat index: u*1024 + v*32 + w
        #pragma unroll 4
        for (int u = 0; u < 32; ++u) {
            const float4* fp = (const float4*)feat[le][u];
            const float4 fA = fp[0];  // f0..f3
            const float4 fB = fp[1];  // f4..f7
            const float4 fC = fp[2];  // f8..f11
            const int idx = wbase + u * 1024;
            const float w000 = W000[idx];
            const float w110 = W110[idx];
            const float w011 = W011[idx];
            const float w101 = W101[idx];
            const float w111 = W111[idx];
            acc0  += w000 * fA.x + w110 * fA.y;
            acc1x += w011 * fA.z + w101 * fB.y + w111 * fC.x;
            acc1y += w011 * fA.w + w101 * fB.z + w111 * fC.y;
            acc1z += w011 * fB.x + w101 * fB.w + w111 * fC.z;
        }
    }

    if (eBase + le < E) {
        const size_t base = (size_t)(eBase + le) * 128;
        out[base + w]              = C_OUT0 * acc0;
        out[base + 32 + 3 * w + 0] = C_OUT1 * acc1x;
        out[base + 32 + 3 * w + 1] = C_OUT1 * acc1y;
        out[base + 32 + 3 * w + 2] = C_OUT1 * acc1z;
    }
}

extern "C" void kernel_launch(void* const* d_in, const int* in_sizes, int n_in,
                              void* d_out, int out_size, void* d_ws, size_t ws_size,
                              hipStream_t stream) {
    const float* x1   = (const float*)d_in[0];
    const float* x2   = (const float*)d_in[1];
    const float* W000 = (const float*)d_in[2];
    const float* W110 = (const float*)d_in[3];
    const float* W011 = (const float*)d_in[4];
    const float* W101 = (const float*)d_in[5];
    const float* W111 = (const float*)d_in[6];
    float* out = (float*)d_out;

    const int E = in_sizes[0] / 128;
    const int grid = (E + EPB - 1) / EPB;
    hipLaunchKernelGGL(e3nn_edge_f32, dim3(grid), dim3(256), 0, stream,
                       x1, x2, W000, W110, W011, W101, W111, out, E);
}

// Round 2
// 99.410 us; speedup vs baseline: 12.5123x; 12.5123x over previous
//
#include <hip/hip_runtime.h>
#include <hip/hip_bf16.h>

// E3nnSimpleEdgeBlock via bf16 MFMA.
//   out0[e,w]   = C0*( sum_uv W000[u,v,w] a0[u]b0[v] + IS3 * sum_uv W110[u,v,w] dot(a1[u],b1[v]) )
//   out1[e,w,k] = C1*( IS3*( sum W011 a0[u]b1[v,k] + sum W101 a1[u,k]b0[v] ) + IS6*sum W111 cross_k )
// GEMM view: M=edges, N=w(32), K=(v,ch,u). A-fragments (pair features) are built
// on the fly in registers; B-fragments (weights, channel scales pre-baked) are
// precomputed in d_ws as a bf16 fragment-ordered stream by prep_weights.
//
// mfma_f32_16x16x32_bf16 lane mapping (m89-verified):
//   A[row=l&15][k=8*(l>>4)+j]  B[k=8*(l>>4)+j][col=l&15]  D[row=4*(l>>4)+r][col=l&15]

typedef __attribute__((ext_vector_type(8))) short short8;   // 8 bf16 (4 VGPRs)
typedef __attribute__((ext_vector_type(4))) float f32x4;    // MFMA accumulator

static constexpr float C_OUT0    = 0.022097086912079608f; // 1/sqrt(2048)
static constexpr float C_OUT1    = 0.03125f;              // 1/sqrt(1024)
static constexpr float INV_SQRT3 = 0.57735026918962576f;
static constexpr float INV_SQRT6 = 0.40824829046386302f;

static __device__ __forceinline__ short bfbits(float x) {
    __hip_bfloat16 h = __float2bfloat16(x);
    return __builtin_bit_cast(short, h);
}

// ---------------------------------------------------------------------------
// prep: permute+prescale weights into bf16 B-fragment stream in d_ws.
// Stream layout: for v in 0..31, frag f in 0..9, lane l in 0..63: 8 bf16.
//   f: 0,1 = W000 nf0/nf1 | 2,3 = W110 | 4,5 = W011 | 6,7 = W101 | 8,9 = W111
//   value = scale * W[(u0+j)*1024 + v*32 + w],  u0=8*(l>>4), w=(f&1)*16+(l&15)
// Total: 32*10*64*8 bf16 = 327680 bytes.
// ---------------------------------------------------------------------------
__global__ __launch_bounds__(256) void prep_weights(
    const float* __restrict__ W000, const float* __restrict__ W110,
    const float* __restrict__ W011, const float* __restrict__ W101,
    const float* __restrict__ W111, short8* __restrict__ wsB)
{
    int t = blockIdx.x * 256 + threadIdx.x;
    if (t >= 32 * 10 * 64) return;
    const int l = t & 63;
    const int f = (t >> 6) % 10;
    const int v = t / 640;
    const int u0 = (l >> 4) * 8;
    const int w  = (f & 1) * 16 + (l & 15);
    const int g  = f >> 1;
    const float* Wp = (g == 0) ? W000 : (g == 1) ? W110 : (g == 2) ? W011
                    : (g == 3) ? W101 : W111;
    const float s = (g == 0) ? C_OUT0
                  : (g == 1) ? C_OUT0 * INV_SQRT3
                  : (g == 4) ? C_OUT1 * INV_SQRT6
                  :            C_OUT1 * INV_SQRT3;
    short8 o;
    #pragma unroll
    for (int j = 0; j < 8; ++j)
        o[j] = bfbits(s * Wp[(size_t)(u0 + j) * 1024 + v * 32 + w]);
    wsB[(v * 10 + f) * 64 + l] = o;
}

// ---------------------------------------------------------------------------
// main kernel: 256 threads = 4 waves; each wave owns 16 edges (block: 64).
// LDS (reused across phases, row stride 132 floats = 33 float4 to kill bank
// conflicts; 2-way max which is free per m136):
//   phase 1: x1 staged as [64][132] floats -> per-lane a-regs
//   phase 2: x2 rearranged as bs[e][v] = float4{b0, b1x, b1y, b1z}
// ---------------------------------------------------------------------------
__global__ __launch_bounds__(256) void e3nn_mfma(
    const float* __restrict__ x1, const float* __restrict__ x2,
    const short8* __restrict__ wsB, float* __restrict__ out, int E)
{
    __shared__ float smemf[64 * 132];
    float4* smem4 = (float4*)smemf;

    const int tid  = threadIdx.x;
    const int l    = tid & 63;
    const int wv   = tid >> 6;
    const int eBase = blockIdx.x * 64;

    // ---- phase 1: stage x1 tile (coalesced float4) ----
    const float4* x1v = (const float4*)x1;
    for (int i = tid; i < 64 * 32; i += 256) {
        const int e = i >> 5, c4 = i & 31;
        float4 val = {0.f, 0.f, 0.f, 0.f};
        if (eBase + e < E) val = x1v[(size_t)(eBase + e) * 32 + c4];
        smem4[e * 33 + c4] = val;
    }
    __syncthreads();

    // ---- hoist per-lane a-values into registers ----
    const int eloc = l & 15;
    const int u0   = (l >> 4) * 8;
    const float* row = smemf + (wv * 16 + eloc) * 132;
    float a0r[8], a1r[3][8];
    #pragma unroll
    for (int j = 0; j < 8; ++j) {
        a0r[j] = row[u0 + j];
        #pragma unroll
        for (int c = 0; c < 3; ++c)
            a1r[c][j] = row[32 + 3 * (u0 + j) + c];
    }
    __syncthreads();

    // ---- phase 2: build bs[e][v] = {b0, b1x, b1y, b1z} (overwrites x1 stage) ----
    for (int i = tid; i < 64 * 128; i += 256) {
        const int e = i >> 7, r = i & 127;
        float val = 0.f;
        if (eBase + e < E) val = x2[(size_t)(eBase + e) * 128 + r];
        if (r < 32) {
            smemf[e * 132 + r * 4] = val;
        } else {
            const int q = r - 32, vv = q / 3, c = q - 3 * vv;
            smemf[e * 132 + vv * 4 + 1 + c] = val;
        }
    }
    __syncthreads();

    // ---- main K loop over v ----
    const f32x4 zero = {0.f, 0.f, 0.f, 0.f};
    f32x4 acc0[2]    = {zero, zero};
    f32x4 acc1[3][2] = {{zero, zero}, {zero, zero}, {zero, zero}};

    const short8* wbase  = wsB + l;
    const float4* bsrow  = smem4 + (wv * 16 + eloc) * 33;

    for (int v = 0; v < 32; ++v) {
        const float4 b = bsrow[v];
        short8 Bf[10];
        #pragma unroll
        for (int i = 0; i < 10; ++i) Bf[i] = wbase[(v * 10 + i) * 64];

        const float bv[3] = {b.y, b.z, b.w};
        short8 A;

        // out0 ch0: a0[u] * b0[v]
        #pragma unroll
        for (int j = 0; j < 8; ++j) A[j] = bfbits(a0r[j] * b.x);
        acc0[0] = __builtin_amdgcn_mfma_f32_16x16x32_bf16(A, Bf[0], acc0[0], 0, 0, 0);
        acc0[1] = __builtin_amdgcn_mfma_f32_16x16x32_bf16(A, Bf[1], acc0[1], 0, 0, 0);

        // out0 ch1: dot(a1[u], b1[v])
        #pragma unroll
        for (int j = 0; j < 8; ++j)
            A[j] = bfbits(a1r[0][j] * b.y + a1r[1][j] * b.z + a1r[2][j] * b.w);
        acc0[0] = __builtin_amdgcn_mfma_f32_16x16x32_bf16(A, Bf[2], acc0[0], 0, 0, 0);
        acc0[1] = __builtin_amdgcn_mfma_f32_16x16x32_bf16(A, Bf[3], acc0[1], 0, 0, 0);

        // out1, k-component kx
        #pragma unroll
        for (int kx = 0; kx < 3; ++kx) {
            const int ii = (kx + 1) % 3, jj = (kx + 2) % 3;
            short8 A011, A101, A111;
            #pragma unroll
            for (int j = 0; j < 8; ++j) {
                A011[j] = bfbits(a0r[j] * bv[kx]);
                A101[j] = bfbits(a1r[kx][j] * b.x);
                A111[j] = bfbits(a1r[ii][j] * bv[jj] - a1r[jj][j] * bv[ii]);
            }
            acc1[kx][0] = __builtin_amdgcn_mfma_f32_16x16x32_bf16(A011, Bf[4], acc1[kx][0], 0, 0, 0);
            acc1[kx][1] = __builtin_amdgcn_mfma_f32_16x16x32_bf16(A011, Bf[5], acc1[kx][1], 0, 0, 0);
            acc1[kx][0] = __builtin_amdgcn_mfma_f32_16x16x32_bf16(A101, Bf[6], acc1[kx][0], 0, 0, 0);
            acc1[kx][1] = __builtin_amdgcn_mfma_f32_16x16x32_bf16(A101, Bf[7], acc1[kx][1], 0, 0, 0);
            acc1[kx][0] = __builtin_amdgcn_mfma_f32_16x16x32_bf16(A111, Bf[8], acc1[kx][0], 0, 0, 0);
            acc1[kx][1] = __builtin_amdgcn_mfma_f32_16x16x32_bf16(A111, Bf[9], acc1[kx][1], 0, 0, 0);
        }
    }

    // ---- epilogue (scales pre-baked into weights) ----
    const int erow0 = (l >> 4) * 4;
    #pragma unroll
    for (int nf = 0; nf < 2; ++nf) {
        const int w = nf * 16 + (l & 15);
        #pragma unroll
        for (int r = 0; r < 4; ++r) {
            const int ge = eBase + wv * 16 + erow0 + r;
            if (ge < E) {
                const size_t base = (size_t)ge * 128;
                out[base + w] = acc0[nf][r];
                #pragma unroll
                for (int kx = 0; kx < 3; ++kx)
                    out[base + 32 + 3 * w + kx] = acc1[kx][nf][r];
            }
        }
    }
}

extern "C" void kernel_launch(void* const* d_in, const int* in_sizes, int n_in,
                              void* d_out, int out_size, void* d_ws, size_t ws_size,
                              hipStream_t stream) {
    const float* x1   = (const float*)d_in[0];
    const float* x2   = (const float*)d_in[1];
    const float* W000 = (const float*)d_in[2];
    const float* W110 = (const float*)d_in[3];
    const float* W011 = (const float*)d_in[4];
    const float* W101 = (const float*)d_in[5];
    const float* W111 = (const float*)d_in[6];
    float* out = (float*)d_out;
    short8* wsB = (short8*)d_ws;   // needs 327680 B

    const int E = in_sizes[0] / 128;

    hipLaunchKernelGGL(prep_weights, dim3((32 * 10 * 64 + 255) / 256), dim3(256), 0, stream,
                       W000, W110, W011, W101, W111, wsB);

    const int grid = (E + 63) / 64;
    hipLaunchKernelGGL(e3nn_mfma, dim3(grid), dim3(256), 0, stream,
                       x1, x2, wsB, out, E);
}